// Round 14
// baseline (329.236 us; speedup 1.0000x reference)
//
#include <hip/hip_runtime.h>
#include <math.h>

#define N_NODES 50000
#define N_EDGES 800000
#define HD 256          // NHEAD * OUT_DIM
#define OUT_DIM 64
#define NHEAD 4
#define SLOPE 0.2f
#define BN_EPS 1e-5f
#define LOG2E 1.4426950408889634f
#define NTILES 391      // ceil(N_NODES / 128)
#define HIST_BLOCKS 384

typedef __attribute__((ext_vector_type(8))) short short8;
typedef __attribute__((ext_vector_type(4))) float float4v;

__device__ __forceinline__ float leaky(float x) { return x >= 0.f ? x : SLOPE * x; }

__device__ __forceinline__ float bf2f(unsigned short u) {
    return __uint_as_float(((unsigned)u) << 16);
}
__device__ __forceinline__ unsigned short f2bf(float f) {
    unsigned u = __float_as_uint(f);
    unsigned r = (u + 0x7fffu + ((u >> 16) & 1u)) >> 16;
    return (unsigned short)r;
}

// pack 8 fp32 -> 8 bf16 (RNE)
__device__ __forceinline__ short8 pack8(const float4 a, const float4 b) {
    short8 r;
    r[0] = (short)f2bf(a.x); r[1] = (short)f2bf(a.y);
    r[2] = (short)f2bf(a.z); r[3] = (short)f2bf(a.w);
    r[4] = (short)f2bf(b.x); r[5] = (short)f2bf(b.y);
    r[6] = (short)f2bf(b.z); r[7] = (short)f2bf(b.w);
    return r;
}

// 16-lane-group sum via DPP row rotations (builtin form; compiler schedules).
template <int CTRL>
__device__ __forceinline__ float ror_add(float v) {
    const int r = __builtin_amdgcn_update_dpp(0, __float_as_int(v), CTRL, 0xF, 0xF, true);
    return v + __int_as_float(r);
}
__device__ __forceinline__ float group16_sum(float v) {
    v = ror_add<0x121>(v);
    v = ror_add<0x122>(v);
    v = ror_add<0x124>(v);
    v = ror_add<0x128>(v);
    return v;
}

// ---------------------------------------------------------------------------
// prep: 3 weight transpose+casts, zero cnt/cursor/sums/done.
// ---------------------------------------------------------------------------
__global__ __launch_bounds__(256) void prep_kernel(const float* __restrict__ W_src,
                                                   const float* __restrict__ W_dst,
                                                   const float* __restrict__ fc_W,
                                                   unsigned short* __restrict__ WtS,
                                                   unsigned short* __restrict__ WtD,
                                                   unsigned short* __restrict__ WtF,
                                                   int* __restrict__ cnt2,
                                                   float* __restrict__ sums,
                                                   int* __restrict__ done) {
    const int b = blockIdx.x;
    const int t = threadIdx.x;
    if (b < 256) {
        WtS[(size_t)b * 256 + t] = f2bf(W_src[(size_t)t * 256 + b]);
    } else if (b < 512) {
        const int n = b - 256;
        WtD[(size_t)n * 256 + t] = f2bf(W_dst[(size_t)t * 256 + n]);
    } else if (b < 576) {
        const int n = b - 512;
        WtF[(size_t)n * 256 + t] = f2bf(fc_W[(size_t)t * 64 + n]);
    } else if (b < 674) {
        const int i = (b - 576) * 256 + t;
        if (i < 25000) ((int4*)cnt2)[i] = make_int4(0, 0, 0, 0);
    } else {
        if (t < 128) sums[t] = 0.f;
        if (t == 128) done[0] = 0;
    }
}

// ---------------------------------------------------------------------------
// bf16 MFMA GEMM: ONE block per 128-row tile, A loaded fp32 ONCE (fused
// cast), then 8 phases = {S,D} x 4 column chunks (r12 form — minimum FETCH)
// + fused edge histogram, now at 384 BLOCKS with int4 dst loads.
// Theory: the 96-block hist was proj's long pole — 800K device-scope atomics
// from only 384 waves (cross-XCD L2 round trips, limited outstanding/wave)
// outlasted the GEMM blocks, which is why occupancy sat at ~15% and every
// pipe counter was diluted across all proj variants. 4x the waves + 4x fewer
// load instructions should pull hist under the GEMM duration.
// ---------------------------------------------------------------------------
__global__ __launch_bounds__(256) void proj_kernel(const float* __restrict__ feat,
                                                   const unsigned short* __restrict__ BtS,
                                                   const unsigned short* __restrict__ BtD,
                                                   const float* __restrict__ bS,
                                                   const float* __restrict__ bD,
                                                   unsigned short* __restrict__ CS,
                                                   unsigned short* __restrict__ CD,
                                                   const int* __restrict__ dst,
                                                   int* __restrict__ cnt) {
    __shared__ unsigned short Bs[64 * 256];   // 32 KB

    if (blockIdx.x < HIST_BLOCKS) {
        const int4* d4 = (const int4*)dst;
        for (int i = blockIdx.x * 256 + threadIdx.x; i < N_EDGES / 4; i += HIST_BLOCKS * 256) {
            const int4 v = d4[i];
            atomicAdd(&cnt[v.x], 1);
            atomicAdd(&cnt[v.y], 1);
            atomicAdd(&cnt[v.z], 1);
            atomicAdd(&cnt[v.w], 1);
        }
        return;
    }

    const int tile = blockIdx.x - HIST_BLOCKS;
    if (tile >= NTILES) return;

    const int t    = threadIdx.x;
    const int w    = t >> 6;
    const int lane = t & 63;
    const int q    = lane >> 4;
    const int l16  = lane & 15;

    const int m0 = tile * 128;

    // ---- load A fragments ONCE as fp32, cast in registers (fused cast) ----
    int ar0 = m0 + w * 32 + l16;
    int ar1 = ar0 + 16;
    if (ar0 > N_NODES - 1) ar0 = N_NODES - 1;
    if (ar1 > N_NODES - 1) ar1 = N_NODES - 1;
    const float* Af0 = feat + (size_t)ar0 * 256 + q * 8;
    const float* Af1 = feat + (size_t)ar1 * 256 + q * 8;
    short8 afr0[8], afr1[8];
#pragma unroll
    for (int kk = 0; kk < 8; ++kk) {
        const float4 x0 = *(const float4*)(Af0 + kk * 32);
        const float4 y0 = *(const float4*)(Af0 + kk * 32 + 4);
        const float4 x1 = *(const float4*)(Af1 + kk * 32);
        const float4 y1 = *(const float4*)(Af1 + kk * 32 + 4);
        afr0[kk] = pack8(x0, y0);
        afr1[kk] = pack8(x1, y1);
    }

    // staging thread mapping (constant across phases)
    const int r   = t >> 2;        // B row (= output col within chunk) 0..63
    const int seg = t & 3;
    const int cc  = r >> 4;
    const int L   = r & 15;

    const int la8 = lane * 8;
    const int lsw[4] = {la8, la8 ^ 16, la8 ^ 32, la8 ^ 48};

    for (int ph = 0; ph < 8; ++ph) {
        const bool isD = (ph >= 4);
        const int  c0  = (ph & 3) * 64;
        const unsigned short* Bt   = isD ? BtD : BtS;
        const float*          bias = isD ? bD  : bS;
        unsigned short*       C    = isD ? CD  : CS;

        __syncthreads();   // prior phase's epilogue LDS reads complete
        // ---- stage B chunk, fragment order, XOR-swizzled ----
        {
            const unsigned short* g = Bt + (size_t)(c0 + r) * 256 + seg * 64;
#pragma unroll
            for (int kk2 = 0; kk2 < 2; ++kk2) {
                const int kk   = seg * 2 + kk2;
                const int c8kk = cc * 8 + kk;
                const int key  = ((c8kk >> 1) & 3) << 4;
#pragma unroll
                for (int q2 = 0; q2 < 4; ++q2)
                    *(short8*)(&Bs[((c8kk * 64 + q2 * 16 + L) * 8) ^ key]) =
                        *(const short8*)(g + kk2 * 32 + q2 * 8);
            }
        }
        __syncthreads();

        float vb[4];
#pragma unroll
        for (int c = 0; c < 4; ++c) vb[c] = bias[c0 + c * 16 + l16];

        float4v a0[4] = {}, a1[4] = {};
#pragma unroll
        for (int kk = 0; kk < 8; ++kk) {
            const short8 af0 = afr0[kk];
            const short8 af1 = afr1[kk];
#pragma unroll
            for (int c = 0; c < 4; ++c) {
                const int c8kk = c * 8 + kk;
                const short8 b = *(const short8*)(&Bs[c8kk * 512 + lsw[(c8kk >> 1) & 3]]);
                a0[c] = __builtin_amdgcn_mfma_f32_16x16x32_bf16(af0, b, a0[c], 0, 0, 0);
                a1[c] = __builtin_amdgcn_mfma_f32_16x16x32_bf16(af1, b, a1[c], 0, 0, 0);
            }
        }

        __syncthreads();   // all waves' MFMA B-reads done before Bs reuse
        // ---- transposing epilogue through LDS (per-wave region) ----
        unsigned short* Cw = Bs + w * 2304;    // 32 rows x 64 cols, stride 72
#pragma unroll
        for (int c = 0; c < 4; ++c) {
            const int cl = c * 16 + l16;
#pragma unroll
            for (int i = 0; i < 4; ++i) {
                Cw[(q * 4 + i) * 72 + cl]      = f2bf(a0[c][i] + vb[c]);
                Cw[(q * 4 + i + 16) * 72 + cl] = f2bf(a1[c][i] + vb[c]);
            }
        }
        // per-wave area: wave-local lgkmcnt ordering, no barrier needed here
#pragma unroll
        for (int j = 0; j < 4; ++j) {
            const int rl = j * 8 + (lane >> 3);    // local row 0..31
            const short8 v = *(const short8*)(Cw + rl * 72 + (lane & 7) * 8);
            const int rg = m0 + w * 32 + rl;
            if (rg < N_NODES)
                *(short8*)(&C[(size_t)rg * 256 + c0 + (lane & 7) * 8]) = v;
        }
    }
}

// ---------------------------------------------------------------------------
// fc GEMM (bf16 MFMA, fp32 out) + fused BatchNorm partial-stats epilogue.
// ---------------------------------------------------------------------------
__global__ __launch_bounds__(256) void fc_bn_kernel(const unsigned short* __restrict__ A,
                                                    const unsigned short* __restrict__ Bt,
                                                    const float* __restrict__ bias,
                                                    float* __restrict__ C,
                                                    float* __restrict__ sums,
                                                    int M) {
    const int w    = threadIdx.x >> 6;
    const int lane = threadIdx.x & 63;
    const int q    = lane >> 4;
    const int l16  = lane & 15;
    const int m0   = blockIdx.x * 64;
    const int t    = threadIdx.x;

    __shared__ float ssum[64], ssq[64];
    if (t < 64) { ssum[t] = 0.f; ssq[t] = 0.f; }

    int arow = m0 + w * 16 + l16;
    if (arow > M - 1) arow = M - 1;
    const unsigned short* Ab  = A  + (size_t)arow * 256 + q * 8;
    const unsigned short* Btb = Bt + (size_t)l16 * 256 + q * 8;

    float4v acc[4] = {};

    for (int k0 = 0; k0 < 256; k0 += 32) {
        const short8 af = *(const short8*)(Ab + k0);
#pragma unroll
        for (int c = 0; c < 4; ++c) {
            const short8 bf = *(const short8*)(Btb + (size_t)c * 16 * 256 + k0);
            acc[c] = __builtin_amdgcn_mfma_f32_16x16x32_bf16(af, bf, acc[c], 0, 0, 0);
        }
    }
    __syncthreads();

#pragma unroll
    for (int c = 0; c < 4; ++c) {
        const int col = c * 16 + l16;
        const float b = bias[col];
        float s = 0.f, qq = 0.f;
#pragma unroll
        for (int i = 0; i < 4; ++i) {
            const int r = m0 + w * 16 + q * 4 + i;
            if (r < M) {
                const float v = acc[c][i] + b;
                C[(size_t)r * 64 + col] = v;
                s += v;
                qq += v * v;
            }
        }
        atomicAdd(&ssum[col], s);
        atomicAdd(&ssq[col], qq);
    }
    __syncthreads();
    if (t < 64) {
        atomicAdd(&sums[t], ssum[t]);
        atomicAdd(&sums[64 + t], ssq[t]);
    }
}

// ---------------------------------------------------------------------------
// CSR build: merged 2-level scan; cursor init (global base offsets);
// slim scatter (ONE random atomic per edge — the atomic returns the slot).
// ---------------------------------------------------------------------------
__global__ __launch_bounds__(512) void scan_kernel(const int* __restrict__ cnt,
                                                   int* __restrict__ offs,
                                                   int* __restrict__ bsum,
                                                   int* __restrict__ bpre,
                                                   int* __restrict__ done) {
    __shared__ int s[512];
    __shared__ bool amLast;
    const int t = threadIdx.x;
    const int i = blockIdx.x * 512 + t;
    const int v = (i < N_NODES) ? cnt[i] : 0;
    s[t] = v;
    __syncthreads();
    for (int off = 1; off < 512; off <<= 1) {
        const int x = (t >= off) ? s[t - off] : 0;
        __syncthreads();
        s[t] += x;
        __syncthreads();
    }
    if (i < N_NODES) offs[i] = s[t] - v;       // exclusive within chunk
    if (t == 511) {
        bsum[blockIdx.x] = s[511];
        __threadfence();
        amLast = (atomicAdd(done, 1) == (int)gridDim.x - 1);
    }
    __syncthreads();
    if (amLast) {
        const int v2 = (t < (int)gridDim.x) ? atomicAdd(&bsum[t], 0) : 0;
        s[t] = v2;
        __syncthreads();
        for (int off = 1; off < 512; off <<= 1) {
            const int x = (t >= off) ? s[t - off] : 0;
            __syncthreads();
            s[t] += x;
            __syncthreads();
        }
        if (t < (int)gridDim.x) bpre[t] = s[t] - v2;
    }
}

__global__ __launch_bounds__(512) void cursor_init_kernel(const int* __restrict__ offs,
                                                          const int* __restrict__ bpre,
                                                          int* __restrict__ cursor) {
    const int i = blockIdx.x * 512 + threadIdx.x;
    if (i < N_NODES) cursor[i] = offs[i] + bpre[i >> 9];
}

__global__ void scatter_kernel(const int* __restrict__ src,
                               const int* __restrict__ dst,
                               int* __restrict__ cursor,
                               int* __restrict__ srcl) {
    const int i = blockIdx.x * 256 + threadIdx.x;
    if (i < N_EDGES) {
        const int p = atomicAdd(&cursor[dst[i]], 1);   // atomic returns slot
        srcl[p] = src[i];
    }
}

// ---------------------------------------------------------------------------
// Fused GATv2 score + softmax + aggregation: one wave per node, 4 nodes per
// 256-thread block. Edge-index loads via SCALAR pipe (readfirstlane on the
// index -> s_load). leaky-dot via free |y| VOP3 modifier; builtin DPP
// reductions; no-max exponentials (|e| << 88; exactly softmax).
// (r12 form — session best: 59.2-59.6 us.)
// ---------------------------------------------------------------------------
__global__ __launch_bounds__(256) void agg_fused_kernel(const unsigned short* __restrict__ h_src,
                                                        const unsigned short* __restrict__ h_dst,
                                                        const int* __restrict__ srcl,
                                                        const int* __restrict__ offs,
                                                        const int* __restrict__ bpre,
                                                        const float* __restrict__ attn,
                                                        const float* __restrict__ out_bias,
                                                        unsigned short* __restrict__ rst) {
    const int node = blockIdx.x * 4 + (threadIdx.x >> 6);
    const int lane = threadIdx.x & 63;
    const int d4 = lane * 4;

    const int beg = offs[node] + bpre[node >> 9];
    const int end = (node + 1 == N_NODES) ? N_EDGES
                                          : (offs[node + 1] + bpre[(node + 1) >> 9]);

    const uint2 hdu = *(const uint2*)(h_dst + (size_t)node * 256 + d4);
    const float hd0 = __uint_as_float(hdu.x << 16);
    const float hd1 = __uint_as_float(hdu.x & 0xffff0000u);
    const float hd2 = __uint_as_float(hdu.y << 16);
    const float hd3 = __uint_as_float(hdu.y & 0xffff0000u);

    const float4 araw = *(const float4*)(attn + d4);
    const float c10 = araw.x * (0.6f * LOG2E), c20 = araw.x * (0.4f * LOG2E);
    const float c11 = araw.y * (0.6f * LOG2E), c21 = araw.y * (0.4f * LOG2E);
    const float c12 = araw.z * (0.6f * LOG2E), c22 = araw.z * (0.4f * LOG2E);
    const float c13 = araw.w * (0.6f * LOG2E), c23 = araw.w * (0.4f * LOG2E);

    float wsum = 0.f, a0 = 0.f, a1 = 0.f, a2 = 0.f, a3 = 0.f;

#define EDGE_BODY(sreg)                                                          \
    {                                                                            \
        const unsigned short* row = h_src + (size_t)(sreg) * 256;                \
        const uint2 u = *(const uint2*)(row + d4);                               \
        const float r0 = __uint_as_float(u.x << 16);                             \
        const float r1 = __uint_as_float(u.x & 0xffff0000u);                     \
        const float r2 = __uint_as_float(u.y << 16);                             \
        const float r3 = __uint_as_float(u.y & 0xffff0000u);                     \
        const float y0 = r0 + hd0, y1 = r1 + hd1, y2 = r2 + hd2, y3 = r3 + hd3;  \
        float pp = fmaf(c10, y0, c20 * __builtin_fabsf(y0));                     \
        pp = fmaf(c11, y1, fmaf(c21, __builtin_fabsf(y1), pp));                  \
        pp = fmaf(c12, y2, fmaf(c22, __builtin_fabsf(y2), pp));                  \
        pp = fmaf(c13, y3, fmaf(c23, __builtin_fabsf(y3), pp));                  \
        pp = group16_sum(pp);                                                    \
        const float wg = __builtin_amdgcn_exp2f(pp);                             \
        wsum += wg;                                                              \
        a0 = fmaf(wg, r0, a0);                                                   \
        a1 = fmaf(wg, r1, a1);                                                   \
        a2 = fmaf(wg, r2, a2);                                                   \
        a3 = fmaf(wg, r3, a3);                                                   \
    }

    int p = beg;
    const int nfull = (end - beg) >> 2;
    for (int it = 0; it < nfull; ++it, p += 4) {
        const int sp = __builtin_amdgcn_readfirstlane(p);   // uniform index
        const int s0 = srcl[sp];                            // -> s_load
        const int s1 = srcl[sp + 1];
        const int s2 = srcl[sp + 2];
        const int s3 = srcl[sp + 3];
        EDGE_BODY(s0);
        EDGE_BODY(s1);
        EDGE_BODY(s2);
        EDGE_BODY(s3);
    }
    for (; p < end; ++p) {
        const int sp = __builtin_amdgcn_readfirstlane(p);
        const int s0 = srcl[sp];
        EDGE_BODY(s0);
    }
#undef EDGE_BODY

    const float inv = (wsum > 0.f) ? 1.f / wsum : 0.f;
    const float4 ob = *(const float4*)(out_bias + d4);
    ushort4 o;
    o.x = f2bf(fmaf(a0, inv, ob.x));
    o.y = f2bf(fmaf(a1, inv, ob.y));
    o.z = f2bf(fmaf(a2, inv, ob.z));
    o.w = f2bf(fmaf(a3, inv, ob.w));
    *(ushort4*)(rst + (size_t)node * 256 + d4) = o;
}

// ---------------------------------------------------------------------------
// BatchNorm finalize + LeakyReLU (float4-vectorized streaming pass)
// ---------------------------------------------------------------------------
__global__ __launch_bounds__(256) void bn_final_kernel(float* __restrict__ z,
                                                       const float* __restrict__ sums,
                                                       const float* __restrict__ gamma,
                                                       const float* __restrict__ beta) {
    const int i = blockIdx.x * 256 + threadIdx.x;    // index of a float4 group
    if (i < N_NODES * 16) {
        const int c4 = (i & 15) * 4;                 // column of first component
        float4 v = ((const float4*)z)[i];
        float out[4] = {v.x, v.y, v.z, v.w};
#pragma unroll
        for (int j = 0; j < 4; ++j) {
            const int col = c4 + j;
            const float mu  = sums[col] * (1.f / N_NODES);
            const float var = sums[64 + col] * (1.f / N_NODES) - mu * mu;
            const float sc  = rsqrtf(var + BN_EPS) * gamma[col];
            const float sh  = beta[col] - mu * sc;
            out[j] = leaky(fmaf(out[j], sc, sh));
        }
        ((float4*)z)[i] = make_float4(out[0], out[1], out[2], out[3]);
    }
}

// ---------------------------------------------------------------------------
extern "C" void kernel_launch(void* const* d_in, const int* in_sizes, int n_in,
                              void* d_out, int out_size, void* d_ws, size_t ws_size,
                              hipStream_t stream) {
    const float* feat    = (const float*)d_in[0];
    const int*   src     = (const int*)  d_in[1];
    const int*   dst     = (const int*)  d_in[2];
    const float* W_src   = (const float*)d_in[3];
    const float* b_src   = (const float*)d_in[4];
    const float* W_dst   = (const float*)d_in[5];
    const float* b_dst   = (const float*)d_in[6];
    const float* attn    = (const float*)d_in[7];
    const float* out_bias= (const float*)d_in[8];
    const float* fc_W    = (const float*)d_in[9];
    const float* fc_b    = (const float*)d_in[10];
    const float* gamma   = (const float*)d_in[11];
    const float* beta    = (const float*)d_in[12];
    float* z = (float*)d_out;

    char* ws = (char*)d_ws;
    size_t off = 0;
    auto carve = [&](size_t bytes) -> void* {
        void* p = ws + off;
        off = (off + bytes + 255) & ~(size_t)255;
        return p;
    };
    unsigned short* h_src_bf= (unsigned short*)carve((size_t)N_NODES * 256 * 2);
    unsigned short* h_dst_bf= (unsigned short*)carve((size_t)N_NODES * 256 * 2);
    unsigned short* rst_bf  = (unsigned short*)carve((size_t)N_NODES * 256 * 2);
    unsigned short* WtS     = (unsigned short*)carve((size_t)256 * 256 * 2);
    unsigned short* WtD     = (unsigned short*)carve((size_t)256 * 256 * 2);
    unsigned short* WtF     = (unsigned short*)carve((size_t)64 * 256 * 2);
    int*   srcl   = (int*)  carve((size_t)N_EDGES * 4);
    int*   cnt    = (int*)  carve((size_t)2 * N_NODES * 4);
    int*   cursor = cnt + N_NODES;
    int*   offs   = (int*)  carve((size_t)(N_NODES + 1) * 4);
    int*   bsum   = (int*)  carve(128 * 4);
    int*   bpre   = (int*)  carve(128 * 4);
    float* sums   = (float*)carve(128 * 4);
    int*   done   = (int*)  carve(64);

    const int nchunks = (N_NODES + 511) / 512;      // 98

    // prep: weight transposes + zeroing
    prep_kernel<<<675, 256, 0, stream>>>(W_src, W_dst, fc_W,
                                         WtS, WtD, WtF, cnt, sums, done);

    // input projections (128-row tiles, fused fp32 cast, 8 phases SxD,
    // swizzled LDS, wide-store epilogue) + fused histogram (384 blk, int4)
    proj_kernel<<<HIST_BLOCKS + NTILES, 256, 0, stream>>>(
        feat, WtS, WtD, b_src, b_dst, h_src_bf, h_dst_bf, dst, cnt);

    // CSR by dst: scan -> cursor init (global bases) -> slim scatter
    scan_kernel<<<nchunks, 512, 0, stream>>>(cnt, offs, bsum, bpre, done);
    cursor_init_kernel<<<nchunks, 512, 0, stream>>>(offs, bpre, cursor);
    scatter_kernel<<<(N_EDGES + 255) / 256, 256, 0, stream>>>(src, dst, cursor, srcl);

    // fused score + softmax + aggregation (1 wave per node, scalar idx loads)
    agg_fused_kernel<<<N_NODES / 4, 256, 0, stream>>>(h_src_bf, h_dst_bf, srcl, offs, bpre,
                                                      attn, out_bias, rst_bf);

    // trailing fc + BN partial stats
    fc_bn_kernel<<<(N_NODES + 63) / 64, 256, 0, stream>>>(rst_bf, WtF, fc_b, z, sums, N_NODES);

    // batchnorm finalize + leaky (vectorized)
    bn_final_kernel<<<(N_NODES * 16 + 255) / 256, 256, 0, stream>>>(z, sums, gamma, beta);
}

// Round 15
// 306.124 us; speedup vs baseline: 1.0755x; 1.0755x over previous
//
#include <hip/hip_runtime.h>
#include <math.h>

#define N_NODES 50000
#define N_EDGES 800000
#define HD 256          // NHEAD * OUT_DIM
#define OUT_DIM 64
#define NHEAD 4
#define SLOPE 0.2f
#define BN_EPS 1e-5f
#define LOG2E 1.4426950408889634f
#define NTILES 391      // ceil(N_NODES / 128)
#define HIST_BLOCKS 96

typedef __attribute__((ext_vector_type(8))) short short8;
typedef __attribute__((ext_vector_type(4))) float float4v;

__device__ __forceinline__ float leaky(float x) { return x >= 0.f ? x : SLOPE * x; }

__device__ __forceinline__ float bf2f(unsigned short u) {
    return __uint_as_float(((unsigned)u) << 16);
}
__device__ __forceinline__ unsigned short f2bf(float f) {
    unsigned u = __float_as_uint(f);
    unsigned r = (u + 0x7fffu + ((u >> 16) & 1u)) >> 16;
    return (unsigned short)r;
}

// pack 8 fp32 -> 8 bf16 (RNE)
__device__ __forceinline__ short8 pack8(const float4 a, const float4 b) {
    short8 r;
    r[0] = (short)f2bf(a.x); r[1] = (short)f2bf(a.y);
    r[2] = (short)f2bf(a.z); r[3] = (short)f2bf(a.w);
    r[4] = (short)f2bf(b.x); r[5] = (short)f2bf(b.y);
    r[6] = (short)f2bf(b.z); r[7] = (short)f2bf(b.w);
    return r;
}

// 16-lane-group sum via DPP row rotations (builtin form; compiler schedules).
template <int CTRL>
__device__ __forceinline__ float ror_add(float v) {
    const int r = __builtin_amdgcn_update_dpp(0, __float_as_int(v), CTRL, 0xF, 0xF, true);
    return v + __int_as_float(r);
}
__device__ __forceinline__ float group16_sum(float v) {
    v = ror_add<0x121>(v);
    v = ror_add<0x122>(v);
    v = ror_add<0x124>(v);
    v = ror_add<0x128>(v);
    return v;
}

// ---------------------------------------------------------------------------
// prep: 3 weight transpose+casts, zero cnt/cursor/sums/done.
// ---------------------------------------------------------------------------
__global__ __launch_bounds__(256) void prep_kernel(const float* __restrict__ W_src,
                                                   const float* __restrict__ W_dst,
                                                   const float* __restrict__ fc_W,
                                                   unsigned short* __restrict__ WtS,
                                                   unsigned short* __restrict__ WtD,
                                                   unsigned short* __restrict__ WtF,
                                                   int* __restrict__ cnt2,
                                                   float* __restrict__ sums,
                                                   int* __restrict__ done) {
    const int b = blockIdx.x;
    const int t = threadIdx.x;
    if (b < 256) {
        WtS[(size_t)b * 256 + t] = f2bf(W_src[(size_t)t * 256 + b]);
    } else if (b < 512) {
        const int n = b - 256;
        WtD[(size_t)n * 256 + t] = f2bf(W_dst[(size_t)t * 256 + n]);
    } else if (b < 576) {
        const int n = b - 512;
        WtF[(size_t)n * 256 + t] = f2bf(fc_W[(size_t)t * 64 + n]);
    } else if (b < 674) {
        const int i = (b - 576) * 256 + t;
        if (i < 25000) ((int4*)cnt2)[i] = make_int4(0, 0, 0, 0);
    } else {
        if (t < 128) sums[t] = 0.f;
        if (t == 128) done[0] = 0;
    }
}

// ---------------------------------------------------------------------------
// bf16 MFMA GEMM: ONE block per 128-row tile, A loaded fp32 ONCE (fused
// cast), then 8 phases = {S,D} x 4 column chunks, + fused edge histogram at
// 96 BLOCKS (verified optimum: 384 blocks regressed — hist blocks fill the
// first dispatch round and serialize on hot counters, delaying GEMM start).
// (Exact r12 form — session best, proj = 60.6 us, FETCH 27.8 MB.)
// ---------------------------------------------------------------------------
__global__ __launch_bounds__(256) void proj_kernel(const float* __restrict__ feat,
                                                   const unsigned short* __restrict__ BtS,
                                                   const unsigned short* __restrict__ BtD,
                                                   const float* __restrict__ bS,
                                                   const float* __restrict__ bD,
                                                   unsigned short* __restrict__ CS,
                                                   unsigned short* __restrict__ CD,
                                                   const int* __restrict__ dst,
                                                   int* __restrict__ cnt) {
    __shared__ unsigned short Bs[64 * 256];   // 32 KB

    if (blockIdx.x < HIST_BLOCKS) {
        for (int i = blockIdx.x * 256 + threadIdx.x; i < N_EDGES; i += HIST_BLOCKS * 256)
            atomicAdd(&cnt[dst[i]], 1);
        return;
    }

    const int tile = blockIdx.x - HIST_BLOCKS;
    if (tile >= NTILES) return;

    const int t    = threadIdx.x;
    const int w    = t >> 6;
    const int lane = t & 63;
    const int q    = lane >> 4;
    const int l16  = lane & 15;

    const int m0 = tile * 128;

    // ---- load A fragments ONCE as fp32, cast in registers (fused cast) ----
    int ar0 = m0 + w * 32 + l16;
    int ar1 = ar0 + 16;
    if (ar0 > N_NODES - 1) ar0 = N_NODES - 1;
    if (ar1 > N_NODES - 1) ar1 = N_NODES - 1;
    const float* Af0 = feat + (size_t)ar0 * 256 + q * 8;
    const float* Af1 = feat + (size_t)ar1 * 256 + q * 8;
    short8 afr0[8], afr1[8];
#pragma unroll
    for (int kk = 0; kk < 8; ++kk) {
        const float4 x0 = *(const float4*)(Af0 + kk * 32);
        const float4 y0 = *(const float4*)(Af0 + kk * 32 + 4);
        const float4 x1 = *(const float4*)(Af1 + kk * 32);
        const float4 y1 = *(const float4*)(Af1 + kk * 32 + 4);
        afr0[kk] = pack8(x0, y0);
        afr1[kk] = pack8(x1, y1);
    }

    // staging thread mapping (constant across phases)
    const int r   = t >> 2;        // B row (= output col within chunk) 0..63
    const int seg = t & 3;
    const int cc  = r >> 4;
    const int L   = r & 15;

    const int la8 = lane * 8;
    const int lsw[4] = {la8, la8 ^ 16, la8 ^ 32, la8 ^ 48};

    for (int ph = 0; ph < 8; ++ph) {
        const bool isD = (ph >= 4);
        const int  c0  = (ph & 3) * 64;
        const unsigned short* Bt   = isD ? BtD : BtS;
        const float*          bias = isD ? bD  : bS;
        unsigned short*       C    = isD ? CD  : CS;

        __syncthreads();   // prior phase's epilogue LDS reads complete
        // ---- stage B chunk, fragment order, XOR-swizzled ----
        {
            const unsigned short* g = Bt + (size_t)(c0 + r) * 256 + seg * 64;
#pragma unroll
            for (int kk2 = 0; kk2 < 2; ++kk2) {
                const int kk   = seg * 2 + kk2;
                const int c8kk = cc * 8 + kk;
                const int key  = ((c8kk >> 1) & 3) << 4;
#pragma unroll
                for (int q2 = 0; q2 < 4; ++q2)
                    *(short8*)(&Bs[((c8kk * 64 + q2 * 16 + L) * 8) ^ key]) =
                        *(const short8*)(g + kk2 * 32 + q2 * 8);
            }
        }
        __syncthreads();

        float vb[4];
#pragma unroll
        for (int c = 0; c < 4; ++c) vb[c] = bias[c0 + c * 16 + l16];

        float4v a0[4] = {}, a1[4] = {};
#pragma unroll
        for (int kk = 0; kk < 8; ++kk) {
            const short8 af0 = afr0[kk];
            const short8 af1 = afr1[kk];
#pragma unroll
            for (int c = 0; c < 4; ++c) {
                const int c8kk = c * 8 + kk;
                const short8 b = *(const short8*)(&Bs[c8kk * 512 + lsw[(c8kk >> 1) & 3]]);
                a0[c] = __builtin_amdgcn_mfma_f32_16x16x32_bf16(af0, b, a0[c], 0, 0, 0);
                a1[c] = __builtin_amdgcn_mfma_f32_16x16x32_bf16(af1, b, a1[c], 0, 0, 0);
            }
        }

        __syncthreads();   // all waves' MFMA B-reads done before Bs reuse
        // ---- transposing epilogue through LDS (per-wave region) ----
        unsigned short* Cw = Bs + w * 2304;    // 32 rows x 64 cols, stride 72
#pragma unroll
        for (int c = 0; c < 4; ++c) {
            const int cl = c * 16 + l16;
#pragma unroll
            for (int i = 0; i < 4; ++i) {
                Cw[(q * 4 + i) * 72 + cl]      = f2bf(a0[c][i] + vb[c]);
                Cw[(q * 4 + i + 16) * 72 + cl] = f2bf(a1[c][i] + vb[c]);
            }
        }
        // per-wave area: wave-local lgkmcnt ordering, no barrier needed here
#pragma unroll
        for (int j = 0; j < 4; ++j) {
            const int rl = j * 8 + (lane >> 3);    // local row 0..31
            const short8 v = *(const short8*)(Cw + rl * 72 + (lane & 7) * 8);
            const int rg = m0 + w * 32 + rl;
            if (rg < N_NODES)
                *(short8*)(&C[(size_t)rg * 256 + c0 + (lane & 7) * 8]) = v;
        }
    }
}

// ---------------------------------------------------------------------------
// fc GEMM (bf16 MFMA, fp32 out) + fused BatchNorm partial-stats epilogue.
// ---------------------------------------------------------------------------
__global__ __launch_bounds__(256) void fc_bn_kernel(const unsigned short* __restrict__ A,
                                                    const unsigned short* __restrict__ Bt,
                                                    const float* __restrict__ bias,
                                                    float* __restrict__ C,
                                                    float* __restrict__ sums,
                                                    int M) {
    const int w    = threadIdx.x >> 6;
    const int lane = threadIdx.x & 63;
    const int q    = lane >> 4;
    const int l16  = lane & 15;
    const int m0   = blockIdx.x * 64;
    const int t    = threadIdx.x;

    __shared__ float ssum[64], ssq[64];
    if (t < 64) { ssum[t] = 0.f; ssq[t] = 0.f; }

    int arow = m0 + w * 16 + l16;
    if (arow > M - 1) arow = M - 1;
    const unsigned short* Ab  = A  + (size_t)arow * 256 + q * 8;
    const unsigned short* Btb = Bt + (size_t)l16 * 256 + q * 8;

    float4v acc[4] = {};

    for (int k0 = 0; k0 < 256; k0 += 32) {
        const short8 af = *(const short8*)(Ab + k0);
#pragma unroll
        for (int c = 0; c < 4; ++c) {
            const short8 bf = *(const short8*)(Btb + (size_t)c * 16 * 256 + k0);
            acc[c] = __builtin_amdgcn_mfma_f32_16x16x32_bf16(af, bf, acc[c], 0, 0, 0);
        }
    }
    __syncthreads();

#pragma unroll
    for (int c = 0; c < 4; ++c) {
        const int col = c * 16 + l16;
        const float b = bias[col];
        float s = 0.f, qq = 0.f;
#pragma unroll
        for (int i = 0; i < 4; ++i) {
            const int r = m0 + w * 16 + q * 4 + i;
            if (r < M) {
                const float v = acc[c][i] + b;
                C[(size_t)r * 64 + col] = v;
                s += v;
                qq += v * v;
            }
        }
        atomicAdd(&ssum[col], s);
        atomicAdd(&ssq[col], qq);
    }
    __syncthreads();
    if (t < 64) {
        atomicAdd(&sums[t], ssum[t]);
        atomicAdd(&sums[64 + t], ssq[t]);
    }
}

// ---------------------------------------------------------------------------
// CSR build: merged 2-level scan; cursor init (global base offsets);
// slim scatter (ONE random atomic per edge — the atomic returns the slot).
// ---------------------------------------------------------------------------
__global__ __launch_bounds__(512) void scan_kernel(const int* __restrict__ cnt,
                                                   int* __restrict__ offs,
                                                   int* __restrict__ bsum,
                                                   int* __restrict__ bpre,
                                                   int* __restrict__ done) {
    __shared__ int s[512];
    __shared__ bool amLast;
    const int t = threadIdx.x;
    const int i = blockIdx.x * 512 + t;
    const int v = (i < N_NODES) ? cnt[i] : 0;
    s[t] = v;
    __syncthreads();
    for (int off = 1; off < 512; off <<= 1) {
        const int x = (t >= off) ? s[t - off] : 0;
        __syncthreads();
        s[t] += x;
        __syncthreads();
    }
    if (i < N_NODES) offs[i] = s[t] - v;       // exclusive within chunk
    if (t == 511) {
        bsum[blockIdx.x] = s[511];
        __threadfence();
        amLast = (atomicAdd(done, 1) == (int)gridDim.x - 1);
    }
    __syncthreads();
    if (amLast) {
        const int v2 = (t < (int)gridDim.x) ? atomicAdd(&bsum[t], 0) : 0;
        s[t] = v2;
        __syncthreads();
        for (int off = 1; off < 512; off <<= 1) {
            const int x = (t >= off) ? s[t - off] : 0;
            __syncthreads();
            s[t] += x;
            __syncthreads();
        }
        if (t < (int)gridDim.x) bpre[t] = s[t] - v2;
    }
}

__global__ __launch_bounds__(512) void cursor_init_kernel(const int* __restrict__ offs,
                                                          const int* __restrict__ bpre,
                                                          int* __restrict__ cursor) {
    const int i = blockIdx.x * 512 + threadIdx.x;
    if (i < N_NODES) cursor[i] = offs[i] + bpre[i >> 9];
}

__global__ void scatter_kernel(const int* __restrict__ src,
                               const int* __restrict__ dst,
                               int* __restrict__ cursor,
                               int* __restrict__ srcl) {
    const int i = blockIdx.x * 256 + threadIdx.x;
    if (i < N_EDGES) {
        const int p = atomicAdd(&cursor[dst[i]], 1);   // atomic returns slot
        srcl[p] = src[i];
    }
}

// ---------------------------------------------------------------------------
// Fused GATv2 score + softmax + aggregation: one wave per node, 4 nodes per
// 256-thread block. Edge-index loads via SCALAR pipe (readfirstlane on the
// index -> s_load). leaky-dot via free |y| VOP3 modifier; builtin DPP
// reductions; no-max exponentials (|e| << 88; exactly softmax).
// (r12 form — session best: 59.2-59.6 us.)
// ---------------------------------------------------------------------------
__global__ __launch_bounds__(256) void agg_fused_kernel(const unsigned short* __restrict__ h_src,
                                                        const unsigned short* __restrict__ h_dst,
                                                        const int* __restrict__ srcl,
                                                        const int* __restrict__ offs,
                                                        const int* __restrict__ bpre,
                                                        const float* __restrict__ attn,
                                                        const float* __restrict__ out_bias,
                                                        unsigned short* __restrict__ rst) {
    const int node = blockIdx.x * 4 + (threadIdx.x >> 6);
    const int lane = threadIdx.x & 63;
    const int d4 = lane * 4;

    const int beg = offs[node] + bpre[node >> 9];
    const int end = (node + 1 == N_NODES) ? N_EDGES
                                          : (offs[node + 1] + bpre[(node + 1) >> 9]);

    const uint2 hdu = *(const uint2*)(h_dst + (size_t)node * 256 + d4);
    const float hd0 = __uint_as_float(hdu.x << 16);
    const float hd1 = __uint_as_float(hdu.x & 0xffff0000u);
    const float hd2 = __uint_as_float(hdu.y << 16);
    const float hd3 = __uint_as_float(hdu.y & 0xffff0000u);

    const float4 araw = *(const float4*)(attn + d4);
    const float c10 = araw.x * (0.6f * LOG2E), c20 = araw.x * (0.4f * LOG2E);
    const float c11 = araw.y * (0.6f * LOG2E), c21 = araw.y * (0.4f * LOG2E);
    const float c12 = araw.z * (0.6f * LOG2E), c22 = araw.z * (0.4f * LOG2E);
    const float c13 = araw.w * (0.6f * LOG2E), c23 = araw.w * (0.4f * LOG2E);

    float wsum = 0.f, a0 = 0.f, a1 = 0.f, a2 = 0.f, a3 = 0.f;

#define EDGE_BODY(sreg)                                                          \
    {                                                                            \
        const unsigned short* row = h_src + (size_t)(sreg) * 256;                \
        const uint2 u = *(const uint2*)(row + d4);                               \
        const float r0 = __uint_as_float(u.x << 16);                             \
        const float r1 = __uint_as_float(u.x & 0xffff0000u);                     \
        const float r2 = __uint_as_float(u.y << 16);                             \
        const float r3 = __uint_as_float(u.y & 0xffff0000u);                     \
        const float y0 = r0 + hd0, y1 = r1 + hd1, y2 = r2 + hd2, y3 = r3 + hd3;  \
        float pp = fmaf(c10, y0, c20 * __builtin_fabsf(y0));                     \
        pp = fmaf(c11, y1, fmaf(c21, __builtin_fabsf(y1), pp));                  \
        pp = fmaf(c12, y2, fmaf(c22, __builtin_fabsf(y2), pp));                  \
        pp = fmaf(c13, y3, fmaf(c23, __builtin_fabsf(y3), pp));                  \
        pp = group16_sum(pp);                                                    \
        const float wg = __builtin_amdgcn_exp2f(pp);                             \
        wsum += wg;                                                              \
        a0 = fmaf(wg, r0, a0);                                                   \
        a1 = fmaf(wg, r1, a1);                                                   \
        a2 = fmaf(wg, r2, a2);                                                   \
        a3 = fmaf(wg, r3, a3);                                                   \
    }

    int p = beg;
    const int nfull = (end - beg) >> 2;
    for (int it = 0; it < nfull; ++it, p += 4) {
        const int sp = __builtin_amdgcn_readfirstlane(p);   // uniform index
        const int s0 = srcl[sp];                            // -> s_load
        const int s1 = srcl[sp + 1];
        const int s2 = srcl[sp + 2];
        const int s3 = srcl[sp + 3];
        EDGE_BODY(s0);
        EDGE_BODY(s1);
        EDGE_BODY(s2);
        EDGE_BODY(s3);
    }
    for (; p < end; ++p) {
        const int sp = __builtin_amdgcn_readfirstlane(p);
        const int s0 = srcl[sp];
        EDGE_BODY(s0);
    }
#undef EDGE_BODY

    const float inv = (wsum > 0.f) ? 1.f / wsum : 0.f;
    const float4 ob = *(const float4*)(out_bias + d4);
    ushort4 o;
    o.x = f2bf(fmaf(a0, inv, ob.x));
    o.y = f2bf(fmaf(a1, inv, ob.y));
    o.z = f2bf(fmaf(a2, inv, ob.z));
    o.w = f2bf(fmaf(a3, inv, ob.w));
    *(ushort4*)(rst + (size_t)node * 256 + d4) = o;
}

// ---------------------------------------------------------------------------
// BatchNorm finalize + LeakyReLU (float4-vectorized streaming pass)
// ---------------------------------------------------------------------------
__global__ __launch_bounds__(256) void bn_final_kernel(float* __restrict__ z,
                                                       const float* __restrict__ sums,
                                                       const float* __restrict__ gamma,
                                                       const float* __restrict__ beta) {
    const int i = blockIdx.x * 256 + threadIdx.x;    // index of a float4 group
    if (i < N_NODES * 16) {
        const int c4 = (i & 15) * 4;                 // column of first component
        float4 v = ((const float4*)z)[i];
        float out[4] = {v.x, v.y, v.z, v.w};
#pragma unroll
        for (int j = 0; j < 4; ++j) {
            const int col = c4 + j;
            const float mu  = sums[col] * (1.f / N_NODES);
            const float var = sums[64 + col] * (1.f / N_NODES) - mu * mu;
            const float sc  = rsqrtf(var + BN_EPS) * gamma[col];
            const float sh  = beta[col] - mu * sc;
            out[j] = leaky(fmaf(out[j], sc, sh));
        }
        ((float4*)z)[i] = make_float4(out[0], out[1], out[2], out[3]);
    }
}

// ---------------------------------------------------------------------------
extern "C" void kernel_launch(void* const* d_in, const int* in_sizes, int n_in,
                              void* d_out, int out_size, void* d_ws, size_t ws_size,
                              hipStream_t stream) {
    const float* feat    = (const float*)d_in[0];
    const int*   src     = (const int*)  d_in[1];
    const int*   dst     = (const int*)  d_in[2];
    const float* W_src   = (const float*)d_in[3];
    const float* b_src   = (const float*)d_in[4];
    const float* W_dst   = (const float*)d_in[5];
    const float* b_dst   = (const float*)d_in[6];
    const float* attn    = (const float*)d_in[7];
    const float* out_bias= (const float*)d_in[8];
    const float* fc_W    = (const float*)d_in[9];
    const float* fc_b    = (const float*)d_in[10];
    const float* gamma   = (const float*)d_in[11];
    const float* beta    = (const float*)d_in[12];
    float* z = (float*)d_out;

    char* ws = (char*)d_ws;
    size_t off = 0;
    auto carve = [&](size_t bytes) -> void* {
        void* p = ws + off;
        off = (off + bytes + 255) & ~(size_t)255;
        return p;
    };
    unsigned short* h_src_bf= (unsigned short*)carve((size_t)N_NODES * 256 * 2);
    unsigned short* h_dst_bf= (unsigned short*)carve((size_t)N_NODES * 256 * 2);
    unsigned short* rst_bf  = (unsigned short*)carve((size_t)N_NODES * 256 * 2);
    unsigned short* WtS     = (unsigned short*)carve((size_t)256 * 256 * 2);
    unsigned short* WtD     = (unsigned short*)carve((size_t)256 * 256 * 2);
    unsigned short* WtF     = (unsigned short*)carve((size_t)64 * 256 * 2);
    int*   srcl   = (int*)  carve((size_t)N_EDGES * 4);
    int*   cnt    = (int*)  carve((size_t)2 * N_NODES * 4);
    int*   cursor = cnt + N_NODES;
    int*   offs   = (int*)  carve((size_t)(N_NODES + 1) * 4);
    int*   bsum   = (int*)  carve(128 * 4);
    int*   bpre   = (int*)  carve(128 * 4);
    float* sums   = (float*)carve(128 * 4);
    int*   done   = (int*)  carve(64);

    const int nchunks = (N_NODES + 511) / 512;      // 98

    // prep: weight transposes + zeroing
    prep_kernel<<<675, 256, 0, stream>>>(W_src, W_dst, fc_W,
                                         WtS, WtD, WtF, cnt, sums, done);

    // input projections (r12 form: 128-row tiles, fused fp32 cast, 8 phases
    // SxD, swizzled LDS, wide-store epilogue) + fused histogram (96 blocks)
    proj_kernel<<<HIST_BLOCKS + NTILES, 256, 0, stream>>>(
        feat, WtS, WtD, b_src, b_dst, h_src_bf, h_dst_bf, dst, cnt);

    // CSR by dst: scan -> cursor init (global bases) -> slim scatter (1-hop)
    scan_kernel<<<nchunks, 512, 0, stream>>>(cnt, offs, bsum, bpre, done);
    cursor_init_kernel<<<nchunks, 512, 0, stream>>>(offs, bpre, cursor);
    scatter_kernel<<<(N_EDGES + 255) / 256, 256, 0, stream>>>(src, dst, cursor, srcl);

    // fused score + softmax + aggregation (1 wave per node, scalar idx loads)
    agg_fused_kernel<<<N_NODES / 4, 256, 0, stream>>>(h_src_bf, h_dst_bf, srcl, offs, bpre,
                                                      attn, out_bias, rst_bf);

    // trailing fc + BN partial stats
    fc_bn_kernel<<<(N_NODES + 63) / 64, 256, 0, stream>>>(rst_bf, WtF, fc_b, z, sums, N_NODES);

    // batchnorm finalize + leaky (vectorized)
    bn_final_kernel<<<(N_NODES * 16 + 255) / 256, 256, 0, stream>>>(z, sums, gamma, beta);
}

// Round 16
// 299.275 us; speedup vs baseline: 1.1001x; 1.0229x over previous
//
#include <hip/hip_runtime.h>
#include <math.h>

#define N_NODES 50000
#define N_EDGES 800000
#define HD 256          // NHEAD * OUT_DIM
#define OUT_DIM 64
#define NHEAD 4
#define SLOPE 0.2f
#define BN_EPS 1e-5f
#define LOG2E 1.4426950408889634f
#define NTILES 391      // ceil(N_NODES / 128)
#define HIST_BLOCKS 96
#define NPART 8
#define PART_SZ 6250    // N_NODES / NPART
#define SCAT_CHUNKS 3125  // ceil(N_EDGES / 256)

typedef __attribute__((ext_vector_type(8))) short short8;
typedef __attribute__((ext_vector_type(4))) float float4v;

__device__ __forceinline__ float leaky(float x) { return x >= 0.f ? x : SLOPE * x; }

__device__ __forceinline__ float bf2f(unsigned short u) {
    return __uint_as_float(((unsigned)u) << 16);
}
__device__ __forceinline__ unsigned short f2bf(float f) {
    unsigned u = __float_as_uint(f);
    unsigned r = (u + 0x7fffu + ((u >> 16) & 1u)) >> 16;
    return (unsigned short)r;
}

// pack 8 fp32 -> 8 bf16 (RNE)
__device__ __forceinline__ short8 pack8(const float4 a, const float4 b) {
    short8 r;
    r[0] = (short)f2bf(a.x); r[1] = (short)f2bf(a.y);
    r[2] = (short)f2bf(a.z); r[3] = (short)f2bf(a.w);
    r[4] = (short)f2bf(b.x); r[5] = (short)f2bf(b.y);
    r[6] = (short)f2bf(b.z); r[7] = (short)f2bf(b.w);
    return r;
}

// 16-lane-group sum via DPP row rotations (builtin form; compiler schedules).
template <int CTRL>
__device__ __forceinline__ float ror_add(float v) {
    const int r = __builtin_amdgcn_update_dpp(0, __float_as_int(v), CTRL, 0xF, 0xF, true);
    return v + __int_as_float(r);
}
__device__ __forceinline__ float group16_sum(float v) {
    v = ror_add<0x121>(v);
    v = ror_add<0x122>(v);
    v = ror_add<0x124>(v);
    v = ror_add<0x128>(v);
    return v;
}

// ---------------------------------------------------------------------------
// prep: 3 weight transpose+casts, zero cnt/cursor/sums/done.
// ---------------------------------------------------------------------------
__global__ __launch_bounds__(256) void prep_kernel(const float* __restrict__ W_src,
                                                   const float* __restrict__ W_dst,
                                                   const float* __restrict__ fc_W,
                                                   unsigned short* __restrict__ WtS,
                                                   unsigned short* __restrict__ WtD,
                                                   unsigned short* __restrict__ WtF,
                                                   int* __restrict__ cnt2,
                                                   float* __restrict__ sums,
                                                   int* __restrict__ done) {
    const int b = blockIdx.x;
    const int t = threadIdx.x;
    if (b < 256) {
        WtS[(size_t)b * 256 + t] = f2bf(W_src[(size_t)t * 256 + b]);
    } else if (b < 512) {
        const int n = b - 256;
        WtD[(size_t)n * 256 + t] = f2bf(W_dst[(size_t)t * 256 + n]);
    } else if (b < 576) {
        const int n = b - 512;
        WtF[(size_t)n * 256 + t] = f2bf(fc_W[(size_t)t * 64 + n]);
    } else if (b < 674) {
        const int i = (b - 576) * 256 + t;
        if (i < 25000) ((int4*)cnt2)[i] = make_int4(0, 0, 0, 0);
    } else {
        if (t < 128) sums[t] = 0.f;
        if (t == 128) done[0] = 0;
    }
}

// ---------------------------------------------------------------------------
// bf16 MFMA GEMM: ONE block per 128-row tile, A loaded fp32 ONCE (fused
// cast), then 8 phases = {S,D} x 4 column chunks, + fused edge histogram at
// 96 BLOCKS (verified optimum). (Exact r12/r15 form — session best.)
// ---------------------------------------------------------------------------
__global__ __launch_bounds__(256) void proj_kernel(const float* __restrict__ feat,
                                                   const unsigned short* __restrict__ BtS,
                                                   const unsigned short* __restrict__ BtD,
                                                   const float* __restrict__ bS,
                                                   const float* __restrict__ bD,
                                                   unsigned short* __restrict__ CS,
                                                   unsigned short* __restrict__ CD,
                                                   const int* __restrict__ dst,
                                                   int* __restrict__ cnt) {
    __shared__ unsigned short Bs[64 * 256];   // 32 KB

    if (blockIdx.x < HIST_BLOCKS) {
        for (int i = blockIdx.x * 256 + threadIdx.x; i < N_EDGES; i += HIST_BLOCKS * 256)
            atomicAdd(&cnt[dst[i]], 1);
        return;
    }

    const int tile = blockIdx.x - HIST_BLOCKS;
    if (tile >= NTILES) return;

    const int t    = threadIdx.x;
    const int w    = t >> 6;
    const int lane = t & 63;
    const int q    = lane >> 4;
    const int l16  = lane & 15;

    const int m0 = tile * 128;

    // ---- load A fragments ONCE as fp32, cast in registers (fused cast) ----
    int ar0 = m0 + w * 32 + l16;
    int ar1 = ar0 + 16;
    if (ar0 > N_NODES - 1) ar0 = N_NODES - 1;
    if (ar1 > N_NODES - 1) ar1 = N_NODES - 1;
    const float* Af0 = feat + (size_t)ar0 * 256 + q * 8;
    const float* Af1 = feat + (size_t)ar1 * 256 + q * 8;
    short8 afr0[8], afr1[8];
#pragma unroll
    for (int kk = 0; kk < 8; ++kk) {
        const float4 x0 = *(const float4*)(Af0 + kk * 32);
        const float4 y0 = *(const float4*)(Af0 + kk * 32 + 4);
        const float4 x1 = *(const float4*)(Af1 + kk * 32);
        const float4 y1 = *(const float4*)(Af1 + kk * 32 + 4);
        afr0[kk] = pack8(x0, y0);
        afr1[kk] = pack8(x1, y1);
    }

    // staging thread mapping (constant across phases)
    const int r   = t >> 2;        // B row (= output col within chunk) 0..63
    const int seg = t & 3;
    const int cc  = r >> 4;
    const int L   = r & 15;

    const int la8 = lane * 8;
    const int lsw[4] = {la8, la8 ^ 16, la8 ^ 32, la8 ^ 48};

    for (int ph = 0; ph < 8; ++ph) {
        const bool isD = (ph >= 4);
        const int  c0  = (ph & 3) * 64;
        const unsigned short* Bt   = isD ? BtD : BtS;
        const float*          bias = isD ? bD  : bS;
        unsigned short*       C    = isD ? CD  : CS;

        __syncthreads();   // prior phase's epilogue LDS reads complete
        // ---- stage B chunk, fragment order, XOR-swizzled ----
        {
            const unsigned short* g = Bt + (size_t)(c0 + r) * 256 + seg * 64;
#pragma unroll
            for (int kk2 = 0; kk2 < 2; ++kk2) {
                const int kk   = seg * 2 + kk2;
                const int c8kk = cc * 8 + kk;
                const int key  = ((c8kk >> 1) & 3) << 4;
#pragma unroll
                for (int q2 = 0; q2 < 4; ++q2)
                    *(short8*)(&Bs[((c8kk * 64 + q2 * 16 + L) * 8) ^ key]) =
                        *(const short8*)(g + kk2 * 32 + q2 * 8);
            }
        }
        __syncthreads();

        float vb[4];
#pragma unroll
        for (int c = 0; c < 4; ++c) vb[c] = bias[c0 + c * 16 + l16];

        float4v a0[4] = {}, a1[4] = {};
#pragma unroll
        for (int kk = 0; kk < 8; ++kk) {
            const short8 af0 = afr0[kk];
            const short8 af1 = afr1[kk];
#pragma unroll
            for (int c = 0; c < 4; ++c) {
                const int c8kk = c * 8 + kk;
                const short8 b = *(const short8*)(&Bs[c8kk * 512 + lsw[(c8kk >> 1) & 3]]);
                a0[c] = __builtin_amdgcn_mfma_f32_16x16x32_bf16(af0, b, a0[c], 0, 0, 0);
                a1[c] = __builtin_amdgcn_mfma_f32_16x16x32_bf16(af1, b, a1[c], 0, 0, 0);
            }
        }

        __syncthreads();   // all waves' MFMA B-reads done before Bs reuse
        // ---- transposing epilogue through LDS (per-wave region) ----
        unsigned short* Cw = Bs + w * 2304;    // 32 rows x 64 cols, stride 72
#pragma unroll
        for (int c = 0; c < 4; ++c) {
            const int cl = c * 16 + l16;
#pragma unroll
            for (int i = 0; i < 4; ++i) {
                Cw[(q * 4 + i) * 72 + cl]      = f2bf(a0[c][i] + vb[c]);
                Cw[(q * 4 + i + 16) * 72 + cl] = f2bf(a1[c][i] + vb[c]);
            }
        }
        // per-wave area: wave-local lgkmcnt ordering, no barrier needed here
#pragma unroll
        for (int j = 0; j < 4; ++j) {
            const int rl = j * 8 + (lane >> 3);    // local row 0..31
            const short8 v = *(const short8*)(Cw + rl * 72 + (lane & 7) * 8);
            const int rg = m0 + w * 32 + rl;
            if (rg < N_NODES)
                *(short8*)(&C[(size_t)rg * 256 + c0 + (lane & 7) * 8]) = v;
        }
    }
}

// ---------------------------------------------------------------------------
// fc GEMM (bf16 MFMA, fp32 out) + fused BatchNorm partial-stats epilogue.
// ---------------------------------------------------------------------------
__global__ __launch_bounds__(256) void fc_bn_kernel(const unsigned short* __restrict__ A,
                                                    const unsigned short* __restrict__ Bt,
                                                    const float* __restrict__ bias,
                                                    float* __restrict__ C,
                                                    float* __restrict__ sums,
                                                    int M) {
    const int w    = threadIdx.x >> 6;
    const int lane = threadIdx.x & 63;
    const int q    = lane >> 4;
    const int l16  = lane & 15;
    const int m0   = blockIdx.x * 64;
    const int t    = threadIdx.x;

    __shared__ float ssum[64], ssq[64];
    if (t < 64) { ssum[t] = 0.f; ssq[t] = 0.f; }

    int arow = m0 + w * 16 + l16;
    if (arow > M - 1) arow = M - 1;
    const unsigned short* Ab  = A  + (size_t)arow * 256 + q * 8;
    const unsigned short* Btb = Bt + (size_t)l16 * 256 + q * 8;

    float4v acc[4] = {};

    for (int k0 = 0; k0 < 256; k0 += 32) {
        const short8 af = *(const short8*)(Ab + k0);
#pragma unroll
        for (int c = 0; c < 4; ++c) {
            const short8 bf = *(const short8*)(Btb + (size_t)c * 16 * 256 + k0);
            acc[c] = __builtin_amdgcn_mfma_f32_16x16x32_bf16(af, bf, acc[c], 0, 0, 0);
        }
    }
    __syncthreads();

#pragma unroll
    for (int c = 0; c < 4; ++c) {
        const int col = c * 16 + l16;
        const float b = bias[col];
        float s = 0.f, qq = 0.f;
#pragma unroll
        for (int i = 0; i < 4; ++i) {
            const int r = m0 + w * 16 + q * 4 + i;
            if (r < M) {
                const float v = acc[c][i] + b;
                C[(size_t)r * 64 + col] = v;
                s += v;
                qq += v * v;
            }
        }
        atomicAdd(&ssum[col], s);
        atomicAdd(&ssq[col], qq);
    }
    __syncthreads();
    if (t < 64) {
        atomicAdd(&sums[t], ssum[t]);
        atomicAdd(&sums[64 + t], ssq[t]);
    }
}

// ---------------------------------------------------------------------------
// CSR build: merged 2-level scan; cursor init (global base offsets);
// XCD-PARTITIONED slim scatter.
// ---------------------------------------------------------------------------
__global__ __launch_bounds__(512) void scan_kernel(const int* __restrict__ cnt,
                                                   int* __restrict__ offs,
                                                   int* __restrict__ bsum,
                                                   int* __restrict__ bpre,
                                                   int* __restrict__ done) {
    __shared__ int s[512];
    __shared__ bool amLast;
    const int t = threadIdx.x;
    const int i = blockIdx.x * 512 + t;
    const int v = (i < N_NODES) ? cnt[i] : 0;
    s[t] = v;
    __syncthreads();
    for (int off = 1; off < 512; off <<= 1) {
        const int x = (t >= off) ? s[t - off] : 0;
        __syncthreads();
        s[t] += x;
        __syncthreads();
    }
    if (i < N_NODES) offs[i] = s[t] - v;       // exclusive within chunk
    if (t == 511) {
        bsum[blockIdx.x] = s[511];
        __threadfence();
        amLast = (atomicAdd(done, 1) == (int)gridDim.x - 1);
    }
    __syncthreads();
    if (amLast) {
        const int v2 = (t < (int)gridDim.x) ? atomicAdd(&bsum[t], 0) : 0;
        s[t] = v2;
        __syncthreads();
        for (int off = 1; off < 512; off <<= 1) {
            const int x = (t >= off) ? s[t - off] : 0;
            __syncthreads();
            s[t] += x;
            __syncthreads();
        }
        if (t < (int)gridDim.x) bpre[t] = s[t] - v2;
    }
}

__global__ __launch_bounds__(512) void cursor_init_kernel(const int* __restrict__ offs,
                                                          const int* __restrict__ bpre,
                                                          int* __restrict__ cursor) {
    const int i = blockIdx.x * 512 + threadIdx.x;
    if (i < N_NODES) cursor[i] = offs[i] + bpre[i >> 9];
}

// XCD-partitioned scatter: block j = {chunk j>>3, partition j&7}. Under the
// round-robin block->XCD mapping, all blocks of partition p run on XCD p, so
// partition p's srcl region (~400KB) and cursor slice (25KB) are written by
// ONE XCD's L2 only: no cross-XCD partial-line evictions (r12 counters: 56MB
// written for 3.2MB payload = 17x amplification), and cursor atomics go
// local-L2 instead of cross-die. dst is re-read 8x (L2/L3-served, cheap).
// Correctness is mapping-independent: each edge is processed exactly once by
// the unique block whose partition contains its dst.
__global__ __launch_bounds__(256) void scatter_kernel(const int* __restrict__ src,
                                                      const int* __restrict__ dst,
                                                      int* __restrict__ cursor,
                                                      int* __restrict__ srcl) {
    const int part  = blockIdx.x & (NPART - 1);
    const int chunk = blockIdx.x >> 3;
    const int i = chunk * 256 + threadIdx.x;
    if (i < N_EDGES) {
        const int d = dst[i];
        if (d / PART_SZ == part) {
            const int p = atomicAdd(&cursor[d], 1);   // local-L2 atomic
            srcl[p] = src[i];
        }
    }
}

// ---------------------------------------------------------------------------
// Fused GATv2 score + softmax + aggregation: one wave per node, 4 nodes per
// 256-thread block. Edge-index loads via SCALAR pipe (readfirstlane on the
// index -> s_load). leaky-dot via free |y| VOP3 modifier; builtin DPP
// reductions; no-max exponentials (|e| << 88; exactly softmax).
// (r12 form — session best: 59.2-60.9 us.)
// ---------------------------------------------------------------------------
__global__ __launch_bounds__(256) void agg_fused_kernel(const unsigned short* __restrict__ h_src,
                                                        const unsigned short* __restrict__ h_dst,
                                                        const int* __restrict__ srcl,
                                                        const int* __restrict__ offs,
                                                        const int* __restrict__ bpre,
                                                        const float* __restrict__ attn,
                                                        const float* __restrict__ out_bias,
                                                        unsigned short* __restrict__ rst) {
    const int node = blockIdx.x * 4 + (threadIdx.x >> 6);
    const int lane = threadIdx.x & 63;
    const int d4 = lane * 4;

    const int beg = offs[node] + bpre[node >> 9];
    const int end = (node + 1 == N_NODES) ? N_EDGES
                                          : (offs[node + 1] + bpre[(node + 1) >> 9]);

    const uint2 hdu = *(const uint2*)(h_dst + (size_t)node * 256 + d4);
    const float hd0 = __uint_as_float(hdu.x << 16);
    const float hd1 = __uint_as_float(hdu.x & 0xffff0000u);
    const float hd2 = __uint_as_float(hdu.y << 16);
    const float hd3 = __uint_as_float(hdu.y & 0xffff0000u);

    const float4 araw = *(const float4*)(attn + d4);
    const float c10 = araw.x * (0.6f * LOG2E), c20 = araw.x * (0.4f * LOG2E);
    const float c11 = araw.y * (0.6f * LOG2E), c21 = araw.y * (0.4f * LOG2E);
    const float c12 = araw.z * (0.6f * LOG2E), c22 = araw.z * (0.4f * LOG2E);
    const float c13 = araw.w * (0.6f * LOG2E), c23 = araw.w * (0.4f * LOG2E);

    float wsum = 0.f, a0 = 0.f, a1 = 0.f, a2 = 0.f, a3 = 0.f;

#define EDGE_BODY(sreg)                                                          \
    {                                                                            \
        const unsigned short* row = h_src + (size_t)(sreg) * 256;                \
        const uint2 u = *(const uint2*)(row + d4);                               \
        const float r0 = __uint_as_float(u.x << 16);                             \
        const float r1 = __uint_as_float(u.x & 0xffff0000u);                     \
        const float r2 = __uint_as_float(u.y << 16);                             \
        const float r3 = __uint_as_float(u.y & 0xffff0000u);                     \
        const float y0 = r0 + hd0, y1 = r1 + hd1, y2 = r2 + hd2, y3 = r3 + hd3;  \
        float pp = fmaf(c10, y0, c20 * __builtin_fabsf(y0));                     \
        pp = fmaf(c11, y1, fmaf(c21, __builtin_fabsf(y1), pp));                  \
        pp = fmaf(c12, y2, fmaf(c22, __builtin_fabsf(y2), pp));                  \
        pp = fmaf(c13, y3, fmaf(c23, __builtin_fabsf(y3), pp));                  \
        pp = group16_sum(pp);                                                    \
        const float wg = __builtin_amdgcn_exp2f(pp);                             \
        wsum += wg;                                                              \
        a0 = fmaf(wg, r0, a0);                                                   \
        a1 = fmaf(wg, r1, a1);                                                   \
        a2 = fmaf(wg, r2, a2);                                                   \
        a3 = fmaf(wg, r3, a3);                                                   \
    }

    int p = beg;
    const int nfull = (end - beg) >> 2;
    for (int it = 0; it < nfull; ++it, p += 4) {
        const int sp = __builtin_amdgcn_readfirstlane(p);   // uniform index
        const int s0 = srcl[sp];                            // -> s_load
        const int s1 = srcl[sp + 1];
        const int s2 = srcl[sp + 2];
        const int s3 = srcl[sp + 3];
        EDGE_BODY(s0);
        EDGE_BODY(s1);
        EDGE_BODY(s2);
        EDGE_BODY(s3);
    }
    for (; p < end; ++p) {
        const int sp = __builtin_amdgcn_readfirstlane(p);
        const int s0 = srcl[sp];
        EDGE_BODY(s0);
    }
#undef EDGE_BODY

    const float inv = (wsum > 0.f) ? 1.f / wsum : 0.f;
    const float4 ob = *(const float4*)(out_bias + d4);
    ushort4 o;
    o.x = f2bf(fmaf(a0, inv, ob.x));
    o.y = f2bf(fmaf(a1, inv, ob.y));
    o.z = f2bf(fmaf(a2, inv, ob.z));
    o.w = f2bf(fmaf(a3, inv, ob.w));
    *(ushort4*)(rst + (size_t)node * 256 + d4) = o;
}

// ---------------------------------------------------------------------------
// BatchNorm finalize + LeakyReLU (float4-vectorized streaming pass)
// ---------------------------------------------------------------------------
__global__ __launch_bounds__(256) void bn_final_kernel(float* __restrict__ z,
                                                       const float* __restrict__ sums,
                                                       const float* __restrict__ gamma,
                                                       const float* __restrict__ beta) {
    const int i = blockIdx.x * 256 + threadIdx.x;    // index of a float4 group
    if (i < N_NODES * 16) {
        const int c4 = (i & 15) * 4;                 // column of first component
        float4 v = ((const float4*)z)[i];
        float out[4] = {v.x, v.y, v.z, v.w};
#pragma unroll
        for (int j = 0; j < 4; ++j) {
            const int col = c4 + j;
            const float mu  = sums[col] * (1.f / N_NODES);
            const float var = sums[64 + col] * (1.f / N_NODES) - mu * mu;
            const float sc  = rsqrtf(var + BN_EPS) * gamma[col];
            const float sh  = beta[col] - mu * sc;
            out[j] = leaky(fmaf(out[j], sc, sh));
        }
        ((float4*)z)[i] = make_float4(out[0], out[1], out[2], out[3]);
    }
}

// ---------------------------------------------------------------------------
extern "C" void kernel_launch(void* const* d_in, const int* in_sizes, int n_in,
                              void* d_out, int out_size, void* d_ws, size_t ws_size,
                              hipStream_t stream) {
    const float* feat    = (const float*)d_in[0];
    const int*   src     = (const int*)  d_in[1];
    const int*   dst     = (const int*)  d_in[2];
    const float* W_src   = (const float*)d_in[3];
    const float* b_src   = (const float*)d_in[4];
    const float* W_dst   = (const float*)d_in[5];
    const float* b_dst   = (const float*)d_in[6];
    const float* attn    = (const float*)d_in[7];
    const float* out_bias= (const float*)d_in[8];
    const float* fc_W    = (const float*)d_in[9];
    const float* fc_b    = (const float*)d_in[10];
    const float* gamma   = (const float*)d_in[11];
    const float* beta    = (const float*)d_in[12];
    float* z = (float*)d_out;

    char* ws = (char*)d_ws;
    size_t off = 0;
    auto carve = [&](size_t bytes) -> void* {
        void* p = ws + off;
        off = (off + bytes + 255) & ~(size_t)255;
        return p;
    };
    unsigned short* h_src_bf= (unsigned short*)carve((size_t)N_NODES * 256 * 2);
    unsigned short* h_dst_bf= (unsigned short*)carve((size_t)N_NODES * 256 * 2);
    unsigned short* rst_bf  = (unsigned short*)carve((size_t)N_NODES * 256 * 2);
    unsigned short* WtS     = (unsigned short*)carve((size_t)256 * 256 * 2);
    unsigned short* WtD     = (unsigned short*)carve((size_t)256 * 256 * 2);
    unsigned short* WtF     = (unsigned short*)carve((size_t)64 * 256 * 2);
    int*   srcl   = (int*)  carve((size_t)N_EDGES * 4);
    int*   cnt    = (int*)  carve((size_t)2 * N_NODES * 4);
    int*   cursor = cnt + N_NODES;
    int*   offs   = (int*)  carve((size_t)(N_NODES + 1) * 4);
    int*   bsum   = (int*)  carve(128 * 4);
    int*   bpre   = (int*)  carve(128 * 4);
    float* sums   = (float*)carve(128 * 4);
    int*   done   = (int*)  carve(64);

    const int nchunks = (N_NODES + 511) / 512;      // 98

    // prep: weight transposes + zeroing
    prep_kernel<<<675, 256, 0, stream>>>(W_src, W_dst, fc_W,
                                         WtS, WtD, WtF, cnt, sums, done);

    // input projections (r12 form) + fused histogram (96 blocks)
    proj_kernel<<<HIST_BLOCKS + NTILES, 256, 0, stream>>>(
        feat, WtS, WtD, b_src, b_dst, h_src_bf, h_dst_bf, dst, cnt);

    // CSR by dst: scan -> cursor init -> XCD-partitioned slim scatter
    scan_kernel<<<nchunks, 512, 0, stream>>>(cnt, offs, bsum, bpre, done);
    cursor_init_kernel<<<nchunks, 512, 0, stream>>>(offs, bpre, cursor);
    scatter_kernel<<<SCAT_CHUNKS * NPART, 256, 0, stream>>>(src, dst, cursor, srcl);

    // fused score + softmax + aggregation (1 wave per node, scalar idx loads)
    agg_fused_kernel<<<N_NODES / 4, 256, 0, stream>>>(h_src_bf, h_dst_bf, srcl, offs, bpre,
                                                      attn, out_bias, rst_bf);

    // trailing fc + BN partial stats
    fc_bn_kernel<<<(N_NODES + 63) / 64, 256, 0, stream>>>(rst_bf, WtF, fc_b, z, sums, N_NODES);

    // batchnorm finalize + leaky (vectorized)
    bn_final_kernel<<<(N_NODES * 16 + 255) / 256, 256, 0, stream>>>(z, sums, gamma, beta);
}

// Round 17
// 298.044 us; speedup vs baseline: 1.1047x; 1.0041x over previous
//
#include <hip/hip_runtime.h>
#include <math.h>

#define N_NODES 50000
#define N_EDGES 800000
#define HD 256          // NHEAD * OUT_DIM
#define OUT_DIM 64
#define NHEAD 4
#define SLOPE 0.2f
#define BN_EPS 1e-5f
#define LOG2E 1.4426950408889634f
#define NTILES 391      // ceil(N_NODES / 128)
#define HIST_BLOCKS 96
#define NPART 8
#define PART_SZ 6250    // N_NODES / NPART
#define SCAT_CHUNKS 3125  // ceil(N_EDGES / 256)

typedef __attribute__((ext_vector_type(8))) short short8;
typedef __attribute__((ext_vector_type(4))) float float4v;

__device__ __forceinline__ float leaky(float x) { return x >= 0.f ? x : SLOPE * x; }

__device__ __forceinline__ float bf2f(unsigned short u) {
    return __uint_as_float(((unsigned)u) << 16);
}
__device__ __forceinline__ unsigned short f2bf(float f) {
    unsigned u = __float_as_uint(f);
    unsigned r = (u + 0x7fffu + ((u >> 16) & 1u)) >> 16;
    return (unsigned short)r;
}

// pack 8 fp32 -> 8 bf16 (RNE)
__device__ __forceinline__ short8 pack8(const float4 a, const float4 b) {
    short8 r;
    r[0] = (short)f2bf(a.x); r[1] = (short)f2bf(a.y);
    r[2] = (short)f2bf(a.z); r[3] = (short)f2bf(a.w);
    r[4] = (short)f2bf(b.x); r[5] = (short)f2bf(b.y);
    r[6] = (short)f2bf(b.z); r[7] = (short)f2bf(b.w);
    return r;
}

// 16-lane-group sum via DPP row rotations (builtin form; compiler schedules).
template <int CTRL>
__device__ __forceinline__ float ror_add(float v) {
    const int r = __builtin_amdgcn_update_dpp(0, __float_as_int(v), CTRL, 0xF, 0xF, true);
    return v + __int_as_float(r);
}
__device__ __forceinline__ float group16_sum(float v) {
    v = ror_add<0x121>(v);
    v = ror_add<0x122>(v);
    v = ror_add<0x124>(v);
    v = ror_add<0x128>(v);
    return v;
}

// ---------------------------------------------------------------------------
// prep: 3 weight transpose+casts, zero cnt/cursor/sums/done.
// ---------------------------------------------------------------------------
__global__ __launch_bounds__(256) void prep_kernel(const float* __restrict__ W_src,
                                                   const float* __restrict__ W_dst,
                                                   const float* __restrict__ fc_W,
                                                   unsigned short* __restrict__ WtS,
                                                   unsigned short* __restrict__ WtD,
                                                   unsigned short* __restrict__ WtF,
                                                   int* __restrict__ cnt2,
                                                   float* __restrict__ sums,
                                                   int* __restrict__ done) {
    const int b = blockIdx.x;
    const int t = threadIdx.x;
    if (b < 256) {
        WtS[(size_t)b * 256 + t] = f2bf(W_src[(size_t)t * 256 + b]);
    } else if (b < 512) {
        const int n = b - 256;
        WtD[(size_t)n * 256 + t] = f2bf(W_dst[(size_t)t * 256 + n]);
    } else if (b < 576) {
        const int n = b - 512;
        WtF[(size_t)n * 256 + t] = f2bf(fc_W[(size_t)t * 64 + n]);
    } else if (b < 674) {
        const int i = (b - 576) * 256 + t;
        if (i < 25000) ((int4*)cnt2)[i] = make_int4(0, 0, 0, 0);
    } else {
        if (t < 128) sums[t] = 0.f;
        if (t == 128) done[0] = 0;
    }
}

// ---------------------------------------------------------------------------
// bf16 MFMA GEMM: ONE block per 128-row tile, A loaded fp32 ONCE (fused
// cast), then 8 phases = {S,D} x 4 column chunks, + fused edge histogram at
// 96 BLOCKS (verified optimum). (Exact r12/r15 form — session best.)
// ---------------------------------------------------------------------------
__global__ __launch_bounds__(256) void proj_kernel(const float* __restrict__ feat,
                                                   const unsigned short* __restrict__ BtS,
                                                   const unsigned short* __restrict__ BtD,
                                                   const float* __restrict__ bS,
                                                   const float* __restrict__ bD,
                                                   unsigned short* __restrict__ CS,
                                                   unsigned short* __restrict__ CD,
                                                   const int* __restrict__ dst,
                                                   int* __restrict__ cnt) {
    __shared__ unsigned short Bs[64 * 256];   // 32 KB

    if (blockIdx.x < HIST_BLOCKS) {
        for (int i = blockIdx.x * 256 + threadIdx.x; i < N_EDGES; i += HIST_BLOCKS * 256)
            atomicAdd(&cnt[dst[i]], 1);
        return;
    }

    const int tile = blockIdx.x - HIST_BLOCKS;
    if (tile >= NTILES) return;

    const int t    = threadIdx.x;
    const int w    = t >> 6;
    const int lane = t & 63;
    const int q    = lane >> 4;
    const int l16  = lane & 15;

    const int m0 = tile * 128;

    // ---- load A fragments ONCE as fp32, cast in registers (fused cast) ----
    int ar0 = m0 + w * 32 + l16;
    int ar1 = ar0 + 16;
    if (ar0 > N_NODES - 1) ar0 = N_NODES - 1;
    if (ar1 > N_NODES - 1) ar1 = N_NODES - 1;
    const float* Af0 = feat + (size_t)ar0 * 256 + q * 8;
    const float* Af1 = feat + (size_t)ar1 * 256 + q * 8;
    short8 afr0[8], afr1[8];
#pragma unroll
    for (int kk = 0; kk < 8; ++kk) {
        const float4 x0 = *(const float4*)(Af0 + kk * 32);
        const float4 y0 = *(const float4*)(Af0 + kk * 32 + 4);
        const float4 x1 = *(const float4*)(Af1 + kk * 32);
        const float4 y1 = *(const float4*)(Af1 + kk * 32 + 4);
        afr0[kk] = pack8(x0, y0);
        afr1[kk] = pack8(x1, y1);
    }

    // staging thread mapping (constant across phases)
    const int r   = t >> 2;        // B row (= output col within chunk) 0..63
    const int seg = t & 3;
    const int cc  = r >> 4;
    const int L   = r & 15;

    const int la8 = lane * 8;
    const int lsw[4] = {la8, la8 ^ 16, la8 ^ 32, la8 ^ 48};

    for (int ph = 0; ph < 8; ++ph) {
        const bool isD = (ph >= 4);
        const int  c0  = (ph & 3) * 64;
        const unsigned short* Bt   = isD ? BtD : BtS;
        const float*          bias = isD ? bD  : bS;
        unsigned short*       C    = isD ? CD  : CS;

        __syncthreads();   // prior phase's epilogue LDS reads complete
        // ---- stage B chunk, fragment order, XOR-swizzled ----
        {
            const unsigned short* g = Bt + (size_t)(c0 + r) * 256 + seg * 64;
#pragma unroll
            for (int kk2 = 0; kk2 < 2; ++kk2) {
                const int kk   = seg * 2 + kk2;
                const int c8kk = cc * 8 + kk;
                const int key  = ((c8kk >> 1) & 3) << 4;
#pragma unroll
                for (int q2 = 0; q2 < 4; ++q2)
                    *(short8*)(&Bs[((c8kk * 64 + q2 * 16 + L) * 8) ^ key]) =
                        *(const short8*)(g + kk2 * 32 + q2 * 8);
            }
        }
        __syncthreads();

        float vb[4];
#pragma unroll
        for (int c = 0; c < 4; ++c) vb[c] = bias[c0 + c * 16 + l16];

        float4v a0[4] = {}, a1[4] = {};
#pragma unroll
        for (int kk = 0; kk < 8; ++kk) {
            const short8 af0 = afr0[kk];
            const short8 af1 = afr1[kk];
#pragma unroll
            for (int c = 0; c < 4; ++c) {
                const int c8kk = c * 8 + kk;
                const short8 b = *(const short8*)(&Bs[c8kk * 512 + lsw[(c8kk >> 1) & 3]]);
                a0[c] = __builtin_amdgcn_mfma_f32_16x16x32_bf16(af0, b, a0[c], 0, 0, 0);
                a1[c] = __builtin_amdgcn_mfma_f32_16x16x32_bf16(af1, b, a1[c], 0, 0, 0);
            }
        }

        __syncthreads();   // all waves' MFMA B-reads done before Bs reuse
        // ---- transposing epilogue through LDS (per-wave region) ----
        unsigned short* Cw = Bs + w * 2304;    // 32 rows x 64 cols, stride 72
#pragma unroll
        for (int c = 0; c < 4; ++c) {
            const int cl = c * 16 + l16;
#pragma unroll
            for (int i = 0; i < 4; ++i) {
                Cw[(q * 4 + i) * 72 + cl]      = f2bf(a0[c][i] + vb[c]);
                Cw[(q * 4 + i + 16) * 72 + cl] = f2bf(a1[c][i] + vb[c]);
            }
        }
        // per-wave area: wave-local lgkmcnt ordering, no barrier needed here
#pragma unroll
        for (int j = 0; j < 4; ++j) {
            const int rl = j * 8 + (lane >> 3);    // local row 0..31
            const short8 v = *(const short8*)(Cw + rl * 72 + (lane & 7) * 8);
            const int rg = m0 + w * 32 + rl;
            if (rg < N_NODES)
                *(short8*)(&C[(size_t)rg * 256 + c0 + (lane & 7) * 8]) = v;
        }
    }
}

// ---------------------------------------------------------------------------
// fc GEMM (bf16 MFMA, fp32 out) + fused BatchNorm partial-stats epilogue.
// ---------------------------------------------------------------------------
__global__ __launch_bounds__(256) void fc_bn_kernel(const unsigned short* __restrict__ A,
                                                    const unsigned short* __restrict__ Bt,
                                                    const float* __restrict__ bias,
                                                    float* __restrict__ C,
                                                    float* __restrict__ sums,
                                                    int M) {
    const int w    = threadIdx.x >> 6;
    const int lane = threadIdx.x & 63;
    const int q    = lane >> 4;
    const int l16  = lane & 15;
    const int m0   = blockIdx.x * 64;
    const int t    = threadIdx.x;

    __shared__ float ssum[64], ssq[64];
    if (t < 64) { ssum[t] = 0.f; ssq[t] = 0.f; }

    int arow = m0 + w * 16 + l16;
    if (arow > M - 1) arow = M - 1;
    const unsigned short* Ab  = A  + (size_t)arow * 256 + q * 8;
    const unsigned short* Btb = Bt + (size_t)l16 * 256 + q * 8;

    float4v acc[4] = {};

    for (int k0 = 0; k0 < 256; k0 += 32) {
        const short8 af = *(const short8*)(Ab + k0);
#pragma unroll
        for (int c = 0; c < 4; ++c) {
            const short8 bf = *(const short8*)(Btb + (size_t)c * 16 * 256 + k0);
            acc[c] = __builtin_amdgcn_mfma_f32_16x16x32_bf16(af, bf, acc[c], 0, 0, 0);
        }
    }
    __syncthreads();

#pragma unroll
    for (int c = 0; c < 4; ++c) {
        const int col = c * 16 + l16;
        const float b = bias[col];
        float s = 0.f, qq = 0.f;
#pragma unroll
        for (int i = 0; i < 4; ++i) {
            const int r = m0 + w * 16 + q * 4 + i;
            if (r < M) {
                const float v = acc[c][i] + b;
                C[(size_t)r * 64 + col] = v;
                s += v;
                qq += v * v;
            }
        }
        atomicAdd(&ssum[col], s);
        atomicAdd(&ssq[col], qq);
    }
    __syncthreads();
    if (t < 64) {
        atomicAdd(&sums[t], ssum[t]);
        atomicAdd(&sums[64 + t], ssq[t]);
    }
}

// ---------------------------------------------------------------------------
// CSR build: merged 2-level scan; cursor init (global base offsets);
// XCD-PARTITIONED slim scatter.
// ---------------------------------------------------------------------------
__global__ __launch_bounds__(512) void scan_kernel(const int* __restrict__ cnt,
                                                   int* __restrict__ offs,
                                                   int* __restrict__ bsum,
                                                   int* __restrict__ bpre,
                                                   int* __restrict__ done) {
    __shared__ int s[512];
    __shared__ bool amLast;
    const int t = threadIdx.x;
    const int i = blockIdx.x * 512 + t;
    const int v = (i < N_NODES) ? cnt[i] : 0;
    s[t] = v;
    __syncthreads();
    for (int off = 1; off < 512; off <<= 1) {
        const int x = (t >= off) ? s[t - off] : 0;
        __syncthreads();
        s[t] += x;
        __syncthreads();
    }
    if (i < N_NODES) offs[i] = s[t] - v;       // exclusive within chunk
    if (t == 511) {
        bsum[blockIdx.x] = s[511];
        __threadfence();
        amLast = (atomicAdd(done, 1) == (int)gridDim.x - 1);
    }
    __syncthreads();
    if (amLast) {
        const int v2 = (t < (int)gridDim.x) ? atomicAdd(&bsum[t], 0) : 0;
        s[t] = v2;
        __syncthreads();
        for (int off = 1; off < 512; off <<= 1) {
            const int x = (t >= off) ? s[t - off] : 0;
            __syncthreads();
            s[t] += x;
            __syncthreads();
        }
        if (t < (int)gridDim.x) bpre[t] = s[t] - v2;
    }
}

__global__ __launch_bounds__(512) void cursor_init_kernel(const int* __restrict__ offs,
                                                          const int* __restrict__ bpre,
                                                          int* __restrict__ cursor) {
    const int i = blockIdx.x * 512 + threadIdx.x;
    if (i < N_NODES) cursor[i] = offs[i] + bpre[i >> 9];
}

// XCD-partitioned scatter: block j = {chunk j>>3, partition j&7}. All blocks
// of partition p run on XCD p (round-robin id%8), so partition p's srcl
// region and cursor slice are written by ONE XCD's L2 only: no cross-XCD
// partial-line evictions, local-L2 atomics. (r16 verified: -7us vs flat.)
__global__ __launch_bounds__(256) void scatter_kernel(const int* __restrict__ src,
                                                      const int* __restrict__ dst,
                                                      int* __restrict__ cursor,
                                                      int* __restrict__ srcl) {
    const int part  = blockIdx.x & (NPART - 1);
    const int chunk = blockIdx.x >> 3;
    const int i = chunk * 256 + threadIdx.x;
    if (i < N_EDGES) {
        const int d = dst[i];
        if (d / PART_SZ == part) {
            const int p = atomicAdd(&cursor[d], 1);   // local-L2 atomic
            srcl[p] = src[i];
        }
    }
}

// ---------------------------------------------------------------------------
// Fused GATv2 score + softmax + aggregation: one wave per node, TWO nodes
// per 128-thread block (was 4/256): block retires on max-of-2 degree sums
// instead of max-of-4 — finer tail granularity, 25K blocks for scheduler
// packing. Per-wave code identical to the verified r12 form (scalar-pipe
// edge-index loads, |y| VOP3 leaky-dot, builtin DPP reductions, no-max exp).
// ---------------------------------------------------------------------------
__global__ __launch_bounds__(128) void agg_fused_kernel(const unsigned short* __restrict__ h_src,
                                                        const unsigned short* __restrict__ h_dst,
                                                        const int* __restrict__ srcl,
                                                        const int* __restrict__ offs,
                                                        const int* __restrict__ bpre,
                                                        const float* __restrict__ attn,
                                                        const float* __restrict__ out_bias,
                                                        unsigned short* __restrict__ rst) {
    const int node = blockIdx.x * 2 + (threadIdx.x >> 6);
    const int lane = threadIdx.x & 63;
    const int d4 = lane * 4;

    const int beg = offs[node] + bpre[node >> 9];
    const int end = (node + 1 == N_NODES) ? N_EDGES
                                          : (offs[node + 1] + bpre[(node + 1) >> 9]);

    const uint2 hdu = *(const uint2*)(h_dst + (size_t)node * 256 + d4);
    const float hd0 = __uint_as_float(hdu.x << 16);
    const float hd1 = __uint_as_float(hdu.x & 0xffff0000u);
    const float hd2 = __uint_as_float(hdu.y << 16);
    const float hd3 = __uint_as_float(hdu.y & 0xffff0000u);

    const float4 araw = *(const float4*)(attn + d4);
    const float c10 = araw.x * (0.6f * LOG2E), c20 = araw.x * (0.4f * LOG2E);
    const float c11 = araw.y * (0.6f * LOG2E), c21 = araw.y * (0.4f * LOG2E);
    const float c12 = araw.z * (0.6f * LOG2E), c22 = araw.z * (0.4f * LOG2E);
    const float c13 = araw.w * (0.6f * LOG2E), c23 = araw.w * (0.4f * LOG2E);

    float wsum = 0.f, a0 = 0.f, a1 = 0.f, a2 = 0.f, a3 = 0.f;

#define EDGE_BODY(sreg)                                                          \
    {                                                                            \
        const unsigned short* row = h_src + (size_t)(sreg) * 256;                \
        const uint2 u = *(const uint2*)(row + d4);                               \
        const float r0 = __uint_as_float(u.x << 16);                             \
        const float r1 = __uint_as_float(u.x & 0xffff0000u);                     \
        const float r2 = __uint_as_float(u.y << 16);                             \
        const float r3 = __uint_as_float(u.y & 0xffff0000u);                     \
        const float y0 = r0 + hd0, y1 = r1 + hd1, y2 = r2 + hd2, y3 = r3 + hd3;  \
        float pp = fmaf(c10, y0, c20 * __builtin_fabsf(y0));                     \
        pp = fmaf(c11, y1, fmaf(c21, __builtin_fabsf(y1), pp));                  \
        pp = fmaf(c12, y2, fmaf(c22, __builtin_fabsf(y2), pp));                  \
        pp = fmaf(c13, y3, fmaf(c23, __builtin_fabsf(y3), pp));                  \
        pp = group16_sum(pp);                                                    \
        const float wg = __builtin_amdgcn_exp2f(pp);                             \
        wsum += wg;                                                              \
        a0 = fmaf(wg, r0, a0);                                                   \
        a1 = fmaf(wg, r1, a1);                                                   \
        a2 = fmaf(wg, r2, a2);                                                   \
        a3 = fmaf(wg, r3, a3);                                                   \
    }

    int p = beg;
    const int nfull = (end - beg) >> 2;
    for (int it = 0; it < nfull; ++it, p += 4) {
        const int sp = __builtin_amdgcn_readfirstlane(p);   // uniform index
        const int s0 = srcl[sp];                            // -> s_load
        const int s1 = srcl[sp + 1];
        const int s2 = srcl[sp + 2];
        const int s3 = srcl[sp + 3];
        EDGE_BODY(s0);
        EDGE_BODY(s1);
        EDGE_BODY(s2);
        EDGE_BODY(s3);
    }
    for (; p < end; ++p) {
        const int sp = __builtin_amdgcn_readfirstlane(p);
        const int s0 = srcl[sp];
        EDGE_BODY(s0);
    }
#undef EDGE_BODY

    const float inv = (wsum > 0.f) ? 1.f / wsum : 0.f;
    const float4 ob = *(const float4*)(out_bias + d4);
    ushort4 o;
    o.x = f2bf(fmaf(a0, inv, ob.x));
    o.y = f2bf(fmaf(a1, inv, ob.y));
    o.z = f2bf(fmaf(a2, inv, ob.z));
    o.w = f2bf(fmaf(a3, inv, ob.w));
    *(ushort4*)(rst + (size_t)node * 256 + d4) = o;
}

// ---------------------------------------------------------------------------
// BatchNorm finalize + LeakyReLU (float4-vectorized streaming pass)
// ---------------------------------------------------------------------------
__global__ __launch_bounds__(256) void bn_final_kernel(float* __restrict__ z,
                                                       const float* __restrict__ sums,
                                                       const float* __restrict__ gamma,
                                                       const float* __restrict__ beta) {
    const int i = blockIdx.x * 256 + threadIdx.x;    // index of a float4 group
    if (i < N_NODES * 16) {
        const int c4 = (i & 15) * 4;                 // column of first component
        float4 v = ((const float4*)z)[i];
        float out[4] = {v.x, v.y, v.z, v.w};
#pragma unroll
        for (int j = 0; j < 4; ++j) {
            const int col = c4 + j;
            const float mu  = sums[col] * (1.f / N_NODES);
            const float var = sums[64 + col] * (1.f / N_NODES) - mu * mu;
            const float sc  = rsqrtf(var + BN_EPS) * gamma[col];
            const float sh  = beta[col] - mu * sc;
            out[j] = leaky(fmaf(out[j], sc, sh));
        }
        ((float4*)z)[i] = make_float4(out[0], out[1], out[2], out[3]);
    }
}

// ---------------------------------------------------------------------------
extern "C" void kernel_launch(void* const* d_in, const int* in_sizes, int n_in,
                              void* d_out, int out_size, void* d_ws, size_t ws_size,
                              hipStream_t stream) {
    const float* feat    = (const float*)d_in[0];
    const int*   src     = (const int*)  d_in[1];
    const int*   dst     = (const int*)  d_in[2];
    const float* W_src   = (const float*)d_in[3];
    const float* b_src   = (const float*)d_in[4];
    const float* W_dst   = (const float*)d_in[5];
    const float* b_dst   = (const float*)d_in[6];
    const float* attn    = (const float*)d_in[7];
    const float* out_bias= (const float*)d_in[8];
    const float* fc_W    = (const float*)d_in[9];
    const float* fc_b    = (const float*)d_in[10];
    const float* gamma   = (const float*)d_in[11];
    const float* beta    = (const float*)d_in[12];
    float* z = (float*)d_out;

    char* ws = (char*)d_ws;
    size_t off = 0;
    auto carve = [&](size_t bytes) -> void* {
        void* p = ws + off;
        off = (off + bytes + 255) & ~(size_t)255;
        return p;
    };
    unsigned short* h_src_bf= (unsigned short*)carve((size_t)N_NODES * 256 * 2);
    unsigned short* h_dst_bf= (unsigned short*)carve((size_t)N_NODES * 256 * 2);
    unsigned short* rst_bf  = (unsigned short*)carve((size_t)N_NODES * 256 * 2);
    unsigned short* WtS     = (unsigned short*)carve((size_t)256 * 256 * 2);
    unsigned short* WtD     = (unsigned short*)carve((size_t)256 * 256 * 2);
    unsigned short* WtF     = (unsigned short*)carve((size_t)64 * 256 * 2);
    int*   srcl   = (int*)  carve((size_t)N_EDGES * 4);
    int*   cnt    = (int*)  carve((size_t)2 * N_NODES * 4);
    int*   cursor = cnt + N_NODES;
    int*   offs   = (int*)  carve((size_t)(N_NODES + 1) * 4);
    int*   bsum   = (int*)  carve(128 * 4);
    int*   bpre   = (int*)  carve(128 * 4);
    float* sums   = (float*)carve(128 * 4);
    int*   done   = (int*)  carve(64);

    const int nchunks = (N_NODES + 511) / 512;      // 98

    // prep: weight transposes + zeroing
    prep_kernel<<<675, 256, 0, stream>>>(W_src, W_dst, fc_W,
                                         WtS, WtD, WtF, cnt, sums, done);

    // input projections (r12 form) + fused histogram (96 blocks)
    proj_kernel<<<HIST_BLOCKS + NTILES, 256, 0, stream>>>(
        feat, WtS, WtD, b_src, b_dst, h_src_bf, h_dst_bf, dst, cnt);

    // CSR by dst: scan -> cursor init -> XCD-partitioned slim scatter
    scan_kernel<<<nchunks, 512, 0, stream>>>(cnt, offs, bsum, bpre, done);
    cursor_init_kernel<<<nchunks, 512, 0, stream>>>(offs, bpre, cursor);
    scatter_kernel<<<SCAT_CHUNKS * NPART, 256, 0, stream>>>(src, dst, cursor, srcl);

    // fused score + softmax + aggregation (1 wave/node, 2 nodes/block)
    agg_fused_kernel<<<N_NODES / 2, 128, 0, stream>>>(h_src_bf, h_dst_bf, srcl, offs, bpre,
                                                      attn, out_bias, rst_bf);

    // trailing fc + BN partial stats
    fc_bn_kernel<<<(N_NODES + 63) / 64, 256, 0, stream>>>(rst_bf, WtF, fc_b, z, sums, N_NODES);

    // batchnorm finalize + leaky (vectorized)
    bn_final_kernel<<<(N_NODES * 16 + 255) / 256, 256, 0, stream>>>(z, sums, gamma, beta);
}